// Round 1
// baseline (251.234 us; speedup 1.0000x reference)
//
#include <hip/hip_runtime.h>
#include <cmath>

// Problem constants (B=4096, D=256, P=100, K=10, n=2B=8192, T=0.2)
#define BB   4096
#define DD   256
#define NN   8192
#define PP   100
#define KK   10

typedef _Float16 f16x8 __attribute__((ext_vector_type(8)));
typedef float    f32x4 __attribute__((ext_vector_type(4)));

// ---------------- workspace layout (bytes) ----------------
constexpr size_t OFF_DENOM = 0;        // double
constexpr size_t OFF_POS   = 8;        // double
constexpr size_t OFF_CNT   = 16;       // 100 int   -> 416
constexpr size_t OFF_MU    = 416;      // 100 f32   -> 816
constexpr size_t OFF_SD    = 816;      // 100 f32   -> 1216
constexpr size_t OFF_PD    = 1216;     // 10000 f32 -> 41216
constexpr size_t OFF_RWN   = 41216;    // 10000 f32 -> 81216
constexpr size_t OFF_R     = 81216;    // 10000 f32 -> 121216
constexpr size_t OFF_WN    = 121216;   // 100*256 f32 -> 223616
constexpr size_t OFF_CTAB  = 223616;   // 8192*100 f32 -> 3500416
constexpr size_t OFF_G     = 3500416;  // 8192*256 f16 -> 7694720  (16B aligned)

// ---------------- init: zero accumulators & histogram ----------------
__global__ void init_kernel(double* denom, double* pos, int* cnt) {
    int t = threadIdx.x;
    if (t == 0) { denom[0] = 0.0; pos[0] = 0.0; }
    if (t < PP) cnt[t] = 0;
}

// ---------------- normalize x / x_aug rows -> f16 G[8192][256], pos dot ----
__global__ void normalize_kernel(const float* __restrict__ x, const float* __restrict__ xa,
                                 _Float16* __restrict__ G, double* __restrict__ pos_acc) {
    const int i = blockIdx.x;       // 0..4095
    const int t = threadIdx.x;      // 0..255 == D
    float v1 = x[(size_t)i * DD + t];
    float v2 = xa[(size_t)i * DD + t];
    float a = v1 * v1, b = v2 * v2, c = v1 * v2;
#pragma unroll
    for (int off = 32; off > 0; off >>= 1) {
        a += __shfl_down(a, off);
        b += __shfl_down(b, off);
        c += __shfl_down(c, off);
    }
    __shared__ float sa[4], sb[4], sc[4];
    const int lane = t & 63, wv = t >> 6;
    if (lane == 0) { sa[wv] = a; sb[wv] = b; sc[wv] = c; }
    __syncthreads();
    float ta = sa[0] + sa[1] + sa[2] + sa[3];
    float tb = sb[0] + sb[1] + sb[2] + sb[3];
    float tc = sc[0] + sc[1] + sc[2] + sc[3];
    float d1 = fmaxf(sqrtf(ta), 1e-12f);
    float d2 = fmaxf(sqrtf(tb), 1e-12f);
    G[(size_t)i * DD + t]        = (_Float16)(v1 / d1);
    G[(size_t)(i + BB) * DD + t] = (_Float16)(v2 / d2);
    if (t == 0) atomicAdd(pos_acc, (double)(tc / (d1 * d2)));
}

// ---------------- normalize prototype rows -> wn[100][256] f32 ----------------
__global__ void proto_norm_kernel(const float* __restrict__ pw, float* __restrict__ wn) {
    const int r = blockIdx.x;   // 0..99
    const int t = threadIdx.x;  // 0..255
    float v = pw[(size_t)r * DD + t];
    float a = v * v;
#pragma unroll
    for (int off = 32; off > 0; off >>= 1) a += __shfl_down(a, off);
    __shared__ float sa[4];
    const int lane = t & 63, wv = t >> 6;
    if (lane == 0) sa[wv] = a;
    __syncthreads();
    float ta = sa[0] + sa[1] + sa[2] + sa[3];
    float d = fmaxf(sqrtf(ta), 1e-12f);
    wn[(size_t)r * DD + t] = v / d;
}

// ---------------- pd[100][100] = 1 - wn wn^T ----------------
__global__ void pd_kernel(const float* __restrict__ wn, float* __restrict__ pd) {
    const int b = blockIdx.x;   // row
    const int t = threadIdx.x;  // 0..127
    __shared__ float wb[DD];
    wb[t] = wn[(size_t)b * DD + t];
    wb[t + 128] = wn[(size_t)b * DD + t + 128];
    __syncthreads();
    if (t < PP) {
        const float* wc = wn + (size_t)t * DD;
        float dot = 0.f;
        for (int k = 0; k < DD; ++k) dot += wb[k] * wc[k];
        pd[b * PP + t] = 1.0f - dot;
    }
}

// ---------------- histogram of hq ----------------
__global__ void hist_kernel(const int* __restrict__ hq, int* __restrict__ cnt) {
    int idx = blockIdx.x * 256 + threadIdx.x;
    if (idx < NN) atomicAdd(&cnt[hq[idx]], 1);
}

// ---------------- per-class row stats: rwn, mu, sd ----------------
// Row class a: value multiset = { pd[a][b] x (cnt[b] - (b==a)) } U {0}  (the eye-zero)
__global__ void stats_kernel(const float* __restrict__ pd, const int* __restrict__ cnt,
                             float* __restrict__ rwn, float* __restrict__ mu,
                             float* __restrict__ sd) {
    const int a = blockIdx.x;      // 0..99
    const int lane = threadIdx.x;  // 64
    float vmin = 0.f, vmax = 0.f;  // injected eye-zero is always in the multiset
    for (int b = lane; b < PP; b += 64) {
        int cc = cnt[b] - (b == a ? 1 : 0);
        if (cc > 0) {
            float v = pd[a * PP + b];
            vmin = fminf(vmin, v);
            vmax = fmaxf(vmax, v);
        }
    }
#pragma unroll
    for (int off = 32; off > 0; off >>= 1) {
        vmin = fminf(vmin, __shfl_xor(vmin, off));
        vmax = fmaxf(vmax, __shfl_xor(vmax, off));
    }
    const float den = vmax - vmin;
    const float inv = (den > 0.f) ? 1.f / den : 0.f;
    double s1 = 0.0, s2 = 0.0;
    for (int b = lane; b < PP; b += 64) {
        float v = (pd[a * PP + b] - vmin) * inv;
        rwn[a * PP + b] = v;
        int cc = cnt[b] - (b == a ? 1 : 0);
        if (cc > 0) { double dv = v; s1 += cc * dv; s2 += cc * dv * dv; }
    }
    if (lane == 0) { double v0 = (0.0 - (double)vmin) * inv; s1 += v0; s2 += v0 * v0; }
#pragma unroll
    for (int off = 32; off > 0; off >>= 1) {
        s1 += __shfl_xor(s1, off);
        s2 += __shfl_xor(s2, off);
    }
    if (lane == 0) {
        double m = s1 / (double)NN;
        double var = (s2 - (double)NN * m * m) / (double)(NN - 1);
        mu[a] = (float)m;
        sd[a] = (float)sqrt(fmax(var, 0.0));
    }
}

// ---------------- R[a][c] = exp((rwn[a][c]-mu[c])^2 / (2 sd[c]^2)) ----------------
__global__ void r_kernel(const float* __restrict__ rwn, const float* __restrict__ mu,
                         const float* __restrict__ sd, float* __restrict__ R) {
    int a = blockIdx.x, c = threadIdx.x;
    if (c < PP) {
        float d = rwn[a * PP + c] - mu[c];
        float s = sd[c];
        R[a * PP + c] = expf(d * d / (2.0f * s * s));
    }
}

// ---------------- Ctab[i][c] = (c in neg_q[i]) ? R[hq[i]][c] : 0 ----------------
__global__ void ctab_kernel(const int* __restrict__ hq, const int* __restrict__ nq,
                            const float* __restrict__ R, float* __restrict__ Ctab) {
    int idx = blockIdx.x * 256 + threadIdx.x;  // < 819200
    if (idx >= NN * PP) return;
    int i = idx / PP;
    int c = idx - i * PP;
    const int* row = nq + (size_t)i * KK;
    bool m = false;
#pragma unroll
    for (int k = 0; k < KK; ++k) m = m || (row[k] == c);
    Ctab[idx] = m ? R[hq[i] * PP + c] : 0.f;
}

// ---------------- main fused GEMM: denom = sum exp(5*dot)*Ctab[i][hq[j]], i!=j ----
__global__ __launch_bounds__(256) void sim_kernel(
    const _Float16* __restrict__ G, const int* __restrict__ hq,
    const float* __restrict__ Ctab, double* __restrict__ denom_acc) {
    __shared__ alignas(16) _Float16 At[128 * 32];
    __shared__ alignas(16) _Float16 Bt[128 * 32];
    __shared__ float wsum[4];
    const int t = threadIdx.x;
    const int lane = t & 63;
    const int wv = t >> 6;
    const int i0 = blockIdx.y * 128;
    const int j0 = blockIdx.x * 128;
    const int wr = (wv >> 1) * 64;   // wave row offset within tile
    const int wc = (wv & 1) * 64;    // wave col offset within tile
    const int hrow = lane & 15;      // m/n index within 16
    const int quad = lane >> 4;      // 0..3

    f32x4 acc[4][4] = {};

    // staging chunks: chunk c (0..511): row = c>>2, k8 = (c&3)*8 elems; 16B each
    const int c0 = t, c1 = t + 256;
    const int r0 = c0 >> 2, q0 = (c0 & 3) * 8;
    const int r1 = c1 >> 2, q1 = (c1 & 3) * 8;

    for (int kt = 0; kt < 8; ++kt) {
        const int k0 = kt * 32;
        const _Float16* ga0 = G + (size_t)(i0 + r0) * DD + (k0 + q0);
        const _Float16* ga1 = G + (size_t)(i0 + r1) * DD + (k0 + q1);
        const _Float16* gb0 = G + (size_t)(j0 + r0) * DD + (k0 + q0);
        const _Float16* gb1 = G + (size_t)(j0 + r1) * DD + (k0 + q1);
        __builtin_amdgcn_global_load_lds((const __attribute__((address_space(1))) void*)ga0,
                                         (__attribute__((address_space(3))) void*)(At + c0 * 8), 16, 0, 0);
        __builtin_amdgcn_global_load_lds((const __attribute__((address_space(1))) void*)ga1,
                                         (__attribute__((address_space(3))) void*)(At + c1 * 8), 16, 0, 0);
        __builtin_amdgcn_global_load_lds((const __attribute__((address_space(1))) void*)gb0,
                                         (__attribute__((address_space(3))) void*)(Bt + c0 * 8), 16, 0, 0);
        __builtin_amdgcn_global_load_lds((const __attribute__((address_space(1))) void*)gb1,
                                         (__attribute__((address_space(3))) void*)(Bt + c1 * 8), 16, 0, 0);
        __syncthreads();  // drains vmcnt(0) before barrier (compiler-enforced)

        f16x8 af[4], bfr[4];
#pragma unroll
        for (int mi = 0; mi < 4; ++mi)
            af[mi] = *(const f16x8*)(At + (wr + mi * 16 + hrow) * 32 + quad * 8);
#pragma unroll
        for (int ni = 0; ni < 4; ++ni)
            bfr[ni] = *(const f16x8*)(Bt + (wc + ni * 16 + hrow) * 32 + quad * 8);
#pragma unroll
        for (int mi = 0; mi < 4; ++mi)
#pragma unroll
            for (int ni = 0; ni < 4; ++ni)
                acc[mi][ni] = __builtin_amdgcn_mfma_f32_16x16x32_f16(af[mi], bfr[ni], acc[mi][ni], 0, 0, 0);
        __syncthreads();
    }

    // epilogue: C/D layout col = lane&15, row = quad*4 + reg
    int cls[4];
#pragma unroll
    for (int ni = 0; ni < 4; ++ni) cls[ni] = hq[j0 + wc + ni * 16 + hrow];

    float partial = 0.f;
#pragma unroll
    for (int mi = 0; mi < 4; ++mi) {
#pragma unroll
        for (int r = 0; r < 4; ++r) {
            const int gi = i0 + wr + mi * 16 + quad * 4 + r;
            const float* crow = Ctab + (size_t)gi * PP;
#pragma unroll
            for (int ni = 0; ni < 4; ++ni) {
                const int gj = j0 + wc + ni * 16 + hrow;
                float coef = crow[cls[ni]];
                float e = __expf(acc[mi][ni][r] * 5.0f);
                partial += (gi != gj) ? e * coef : 0.f;
            }
        }
    }
#pragma unroll
    for (int off = 32; off > 0; off >>= 1) partial += __shfl_down(partial, off);
    if (lane == 0) wsum[wv] = partial;
    __syncthreads();
    if (t == 0) atomicAdd(denom_acc, (double)(wsum[0] + wsum[1] + wsum[2] + wsum[3]));
}

// ---------------- finalize ----------------
__global__ void finalize_kernel(const double* __restrict__ denom,
                                const double* __restrict__ pos, float* __restrict__ out) {
    // loss = log(denom) - (1/n) * sum_i dot_i/T ; dots duplicated over the two views
    out[0] = (float)(log(denom[0]) - pos[0] * (5.0 / 4096.0));
}

extern "C" void kernel_launch(void* const* d_in, const int* in_sizes, int n_in,
                              void* d_out, int out_size, void* d_ws, size_t ws_size,
                              hipStream_t stream) {
    const float* x  = (const float*)d_in[0];
    const float* xa = (const float*)d_in[1];
    const float* pw = (const float*)d_in[2];
    const int* hq   = (const int*)d_in[3];
    const int* nq   = (const int*)d_in[4];
    float* out      = (float*)d_out;

    char* ws = (char*)d_ws;
    double* denom = (double*)(ws + OFF_DENOM);
    double* pos   = (double*)(ws + OFF_POS);
    int* cnt      = (int*)(ws + OFF_CNT);
    float* mu     = (float*)(ws + OFF_MU);
    float* sd     = (float*)(ws + OFF_SD);
    float* pd     = (float*)(ws + OFF_PD);
    float* rwn    = (float*)(ws + OFF_RWN);
    float* R      = (float*)(ws + OFF_R);
    float* wn     = (float*)(ws + OFF_WN);
    float* Ctab   = (float*)(ws + OFF_CTAB);
    _Float16* G   = (_Float16*)(ws + OFF_G);

    init_kernel<<<1, 128, 0, stream>>>(denom, pos, cnt);
    normalize_kernel<<<BB, DD, 0, stream>>>(x, xa, G, pos);
    proto_norm_kernel<<<PP, DD, 0, stream>>>(pw, wn);
    pd_kernel<<<PP, 128, 0, stream>>>(wn, pd);
    hist_kernel<<<NN / 256, 256, 0, stream>>>(hq, cnt);
    stats_kernel<<<PP, 64, 0, stream>>>(pd, cnt, rwn, mu, sd);
    r_kernel<<<PP, 128, 0, stream>>>(rwn, mu, sd, R);
    ctab_kernel<<<(NN * PP) / 256, 256, 0, stream>>>(hq, nq, R, Ctab);
    sim_kernel<<<dim3(NN / 128, NN / 128), 256, 0, stream>>>(G, hq, Ctab, denom);
    finalize_kernel<<<1, 1, 0, stream>>>(denom, pos, out);
}

// Round 2
// 226.167 us; speedup vs baseline: 1.1108x; 1.1108x over previous
//
#include <hip/hip_runtime.h>
#include <cmath>

// Problem constants (B=4096, D=256, P=100, K=10, n=2B=8192, T=0.2)
#define BB   4096
#define DD   256
#define NN   8192
#define PP   100
#define KK   10

typedef _Float16 f16x8 __attribute__((ext_vector_type(8)));
typedef float    f32x4 __attribute__((ext_vector_type(4)));

// ---------------- workspace layout (bytes) ----------------
constexpr size_t OFF_DPART = 0;            // 64 double -> 512
constexpr size_t OFF_PPART = 512;          // 64 double -> 1024
constexpr size_t OFF_CNT   = 1024;         // 100 int   -> 1424
constexpr size_t OFF_MU    = 1424;         // 100 f32
constexpr size_t OFF_SD    = 1824;         // 100 f32
constexpr size_t OFF_PD    = 2224;         // 10000 f32
constexpr size_t OFF_RWN   = 42224;        // 10000 f32
constexpr size_t OFF_WN    = 82224;        // 100*256 f32
constexpr size_t OFF_CTAB  = 184624;       // 8192*100 f32 -> 3461424
constexpr size_t OFF_G     = 3461440;      // 8192*256 f16 (16B aligned)

// ---------------- init accumulators + histogram (1 block) ----------------
__global__ void init_hist_kernel(const int* __restrict__ hq, int* __restrict__ cnt,
                                 double* __restrict__ dpart, double* __restrict__ ppart) {
    __shared__ int sc[PP];
    const int t = threadIdx.x;  // 256
    if (t < PP) sc[t] = 0;
    if (t < 64) { dpart[t] = 0.0; ppart[t] = 0.0; }
    __syncthreads();
    for (int i = t; i < NN; i += 256) atomicAdd(&sc[hq[i]], 1);
    __syncthreads();
    if (t < PP) cnt[t] = sc[t];
}

// ---------------- normalize x / x_aug rows -> f16 G[8192][256], pos dot ----
__global__ void normalize_kernel(const float* __restrict__ x, const float* __restrict__ xa,
                                 _Float16* __restrict__ G, double* __restrict__ ppart) {
    const int i = blockIdx.x;       // 0..4095
    const int t = threadIdx.x;      // 0..255 == D
    float v1 = x[(size_t)i * DD + t];
    float v2 = xa[(size_t)i * DD + t];
    float a = v1 * v1, b = v2 * v2, c = v1 * v2;
#pragma unroll
    for (int off = 32; off > 0; off >>= 1) {
        a += __shfl_down(a, off);
        b += __shfl_down(b, off);
        c += __shfl_down(c, off);
    }
    __shared__ float sa[4], sb[4], sc[4];
    const int lane = t & 63, wv = t >> 6;
    if (lane == 0) { sa[wv] = a; sb[wv] = b; sc[wv] = c; }
    __syncthreads();
    float ta = sa[0] + sa[1] + sa[2] + sa[3];
    float tb = sb[0] + sb[1] + sb[2] + sb[3];
    float tc = sc[0] + sc[1] + sc[2] + sc[3];
    float d1 = fmaxf(sqrtf(ta), 1e-12f);
    float d2 = fmaxf(sqrtf(tb), 1e-12f);
    G[(size_t)i * DD + t]        = (_Float16)(v1 / d1);
    G[(size_t)(i + BB) * DD + t] = (_Float16)(v2 / d2);
    if (t == 0) atomicAdd(&ppart[i & 63], (double)(tc / (d1 * d2)));
}

// ---------------- normalize prototype rows -> wn[100][256] f32 ----------------
__global__ void proto_norm_kernel(const float* __restrict__ pw, float* __restrict__ wn) {
    const int r = blockIdx.x;   // 0..99
    const int t = threadIdx.x;  // 0..255
    float v = pw[(size_t)r * DD + t];
    float a = v * v;
#pragma unroll
    for (int off = 32; off > 0; off >>= 1) a += __shfl_down(a, off);
    __shared__ float sa[4];
    const int lane = t & 63, wv = t >> 6;
    if (lane == 0) sa[wv] = a;
    __syncthreads();
    float ta = sa[0] + sa[1] + sa[2] + sa[3];
    float d = fmaxf(sqrtf(ta), 1e-12f);
    wn[(size_t)r * DD + t] = v / d;
}

// ---------------- pd[100][100] = 1 - wn wn^T ----------------
__global__ void pd_kernel(const float* __restrict__ wn, float* __restrict__ pd) {
    const int b = blockIdx.x;   // row
    const int t = threadIdx.x;  // 0..127
    __shared__ float wb[DD];
    wb[t] = wn[(size_t)b * DD + t];
    wb[t + 128] = wn[(size_t)b * DD + t + 128];
    __syncthreads();
    if (t < PP) {
        const float* wc = wn + (size_t)t * DD;
        float dot = 0.f;
        for (int k = 0; k < DD; ++k) dot += wb[k] * wc[k];
        pd[b * PP + t] = 1.0f - dot;
    }
}

// ---------------- per-class row stats: rwn, mu, sd ----------------
// Row class a: value multiset = { pd[a][b] x (cnt[b] - (b==a)) } U {0}  (the eye-zero)
__global__ void stats_kernel(const float* __restrict__ pd, const int* __restrict__ cnt,
                             float* __restrict__ rwn, float* __restrict__ mu,
                             float* __restrict__ sd) {
    const int a = blockIdx.x;      // 0..99
    const int lane = threadIdx.x;  // 64
    float vmin = 0.f, vmax = 0.f;  // injected eye-zero is always in the multiset
    for (int b = lane; b < PP; b += 64) {
        int cc = cnt[b] - (b == a ? 1 : 0);
        if (cc > 0) {
            float v = pd[a * PP + b];
            vmin = fminf(vmin, v);
            vmax = fmaxf(vmax, v);
        }
    }
#pragma unroll
    for (int off = 32; off > 0; off >>= 1) {
        vmin = fminf(vmin, __shfl_xor(vmin, off));
        vmax = fmaxf(vmax, __shfl_xor(vmax, off));
    }
    const float den = vmax - vmin;
    const float inv = (den > 0.f) ? 1.f / den : 0.f;
    double s1 = 0.0, s2 = 0.0;
    for (int b = lane; b < PP; b += 64) {
        float v = (pd[a * PP + b] - vmin) * inv;
        rwn[a * PP + b] = v;
        int cc = cnt[b] - (b == a ? 1 : 0);
        if (cc > 0) { double dv = v; s1 += cc * dv; s2 += cc * dv * dv; }
    }
    if (lane == 0) { double v0 = (0.0 - (double)vmin) * inv; s1 += v0; s2 += v0 * v0; }
#pragma unroll
    for (int off = 32; off > 0; off >>= 1) {
        s1 += __shfl_xor(s1, off);
        s2 += __shfl_xor(s2, off);
    }
    if (lane == 0) {
        double m = s1 / (double)NN;
        double var = (s2 - (double)NN * m * m) / (double)(NN - 1);
        mu[a] = (float)m;
        sd[a] = (float)sqrt(fmax(var, 0.0));
    }
}

// ---- Ctab[i][c] = (c in neg_q[i]) ? exp((rwn[hq[i]][c]-mu[c])^2/(2 sd[c]^2)) : 0 ----
__global__ void ctab_kernel(const int* __restrict__ hq, const int* __restrict__ nq,
                            const float* __restrict__ rwn, const float* __restrict__ mu,
                            const float* __restrict__ sd, float* __restrict__ Ctab) {
    int idx = blockIdx.x * 256 + threadIdx.x;  // < 819200
    if (idx >= NN * PP) return;
    int i = idx / PP;
    int c = idx - i * PP;
    const int* row = nq + (size_t)i * KK;
    bool m = false;
#pragma unroll
    for (int k = 0; k < KK; ++k) m = m || (row[k] == c);
    float v = 0.f;
    if (m) {
        float d = rwn[hq[i] * PP + c] - mu[c];
        float s = sd[c];
        v = expf(d * d / (2.0f * s * s));
    }
    Ctab[idx] = v;
}

// ---------------- main fused GEMM over upper-triangular tiles ----------------
// denom = sum_{i!=j} exp(5*dot_ij) * Ctab[i][hq[j]]
//       = sum_{i<j} exp(5*dot_ij) * (Ctab[i][hq[j]] + Ctab[j][hq[i]])  (+ diag tiles)
__global__ __launch_bounds__(256) void sim_kernel(
    const _Float16* __restrict__ G, const int* __restrict__ hq,
    const float* __restrict__ Ctab, double* __restrict__ dpart) {
    const int bi = blockIdx.y, bj = blockIdx.x;
    if (bj < bi) return;                 // upper triangle only
    const bool diag = (bi == bj);

    __shared__ alignas(16) _Float16 At[128 * 32];
    __shared__ alignas(16) _Float16 Bt[128 * 32];
    __shared__ float wsum[4];
    const int t = threadIdx.x;
    const int lane = t & 63;
    const int wv = t >> 6;
    const int i0 = bi * 128;
    const int j0 = bj * 128;
    const int wr = (wv >> 1) * 64;   // wave row offset within tile
    const int wc = (wv & 1) * 64;    // wave col offset within tile
    const int hrow = lane & 15;      // m/n index within 16
    const int quad = lane >> 4;      // 0..3

    f32x4 acc[4][4] = {};

    // staging: chunk c (0..511): row = c>>2, slot q = c&3; 16B each.
    // Bank-conflict swizzle: LDS slot (row,q) holds global chunk q ^ ((row>>1)&3).
    const int c0 = t, c1 = t + 256;
    const int r0 = c0 >> 2, q0 = ((c0 & 3) ^ ((r0 >> 1) & 3)) * 8;
    const int r1 = c1 >> 2, q1 = ((c1 & 3) ^ ((r1 >> 1) & 3)) * 8;

    for (int kt = 0; kt < 8; ++kt) {
        const int k0 = kt * 32;
        const _Float16* ga0 = G + (size_t)(i0 + r0) * DD + (k0 + q0);
        const _Float16* ga1 = G + (size_t)(i0 + r1) * DD + (k0 + q1);
        const _Float16* gb0 = G + (size_t)(j0 + r0) * DD + (k0 + q0);
        const _Float16* gb1 = G + (size_t)(j0 + r1) * DD + (k0 + q1);
        __builtin_amdgcn_global_load_lds((const __attribute__((address_space(1))) void*)ga0,
                                         (__attribute__((address_space(3))) void*)(At + c0 * 8), 16, 0, 0);
        __builtin_amdgcn_global_load_lds((const __attribute__((address_space(1))) void*)ga1,
                                         (__attribute__((address_space(3))) void*)(At + c1 * 8), 16, 0, 0);
        __builtin_amdgcn_global_load_lds((const __attribute__((address_space(1))) void*)gb0,
                                         (__attribute__((address_space(3))) void*)(Bt + c0 * 8), 16, 0, 0);
        __builtin_amdgcn_global_load_lds((const __attribute__((address_space(1))) void*)gb1,
                                         (__attribute__((address_space(3))) void*)(Bt + c1 * 8), 16, 0, 0);
        __syncthreads();

        f16x8 af[4], bfr[4];
#pragma unroll
        for (int mi = 0; mi < 4; ++mi) {
            const int rr = wr + mi * 16 + hrow;
            const int sq = quad ^ ((rr >> 1) & 3);
            af[mi] = *(const f16x8*)(At + rr * 32 + sq * 8);
        }
#pragma unroll
        for (int ni = 0; ni < 4; ++ni) {
            const int rr = wc + ni * 16 + hrow;
            const int sq = quad ^ ((rr >> 1) & 3);
            bfr[ni] = *(const f16x8*)(Bt + rr * 32 + sq * 8);
        }
#pragma unroll
        for (int mi = 0; mi < 4; ++mi)
#pragma unroll
            for (int ni = 0; ni < 4; ++ni)
                acc[mi][ni] = __builtin_amdgcn_mfma_f32_16x16x32_f16(af[mi], bfr[ni], acc[mi][ni], 0, 0, 0);
        __syncthreads();
    }

    // epilogue: C/D layout col = lane&15, row = quad*4 + reg
    int cls_j[4];
#pragma unroll
    for (int ni = 0; ni < 4; ++ni) cls_j[ni] = hq[j0 + wc + ni * 16 + hrow];

    float partial = 0.f;
    if (diag) {
#pragma unroll
        for (int mi = 0; mi < 4; ++mi) {
#pragma unroll
            for (int r = 0; r < 4; ++r) {
                const int gi = i0 + wr + mi * 16 + quad * 4 + r;
                const float* crow = Ctab + (size_t)gi * PP;
#pragma unroll
                for (int ni = 0; ni < 4; ++ni) {
                    const int gj = j0 + wc + ni * 16 + hrow;
                    float e = __expf(acc[mi][ni][r] * 5.0f);
                    partial += (gi != gj) ? e * crow[cls_j[ni]] : 0.f;
                }
            }
        }
    } else {
#pragma unroll
        for (int mi = 0; mi < 4; ++mi) {
#pragma unroll
            for (int r = 0; r < 4; ++r) {
                const int gi = i0 + wr + mi * 16 + quad * 4 + r;
                const float* crow = Ctab + (size_t)gi * PP;
                const int ci = hq[gi];
#pragma unroll
                for (int ni = 0; ni < 4; ++ni) {
                    const int gj = j0 + wc + ni * 16 + hrow;
                    float e = __expf(acc[mi][ni][r] * 5.0f);
                    partial += e * (crow[cls_j[ni]] + Ctab[(size_t)gj * PP + ci]);
                }
            }
        }
    }
#pragma unroll
    for (int off = 32; off > 0; off >>= 1) partial += __shfl_down(partial, off);
    if (lane == 0) wsum[wv] = partial;
    __syncthreads();
    if (t == 0) atomicAdd(&dpart[(bi * 64 + bj) & 63], (double)(wsum[0] + wsum[1] + wsum[2] + wsum[3]));
}

// ---------------- finalize ----------------
__global__ void finalize_kernel(const double* __restrict__ dpart,
                                const double* __restrict__ ppart, float* __restrict__ out) {
    const int lane = threadIdx.x;  // 64
    double d = dpart[lane], p = ppart[lane];
#pragma unroll
    for (int off = 32; off > 0; off >>= 1) {
        d += __shfl_down(d, off);
        p += __shfl_down(p, off);
    }
    if (lane == 0) out[0] = (float)(log(d) - p * (5.0 / 4096.0));
}

extern "C" void kernel_launch(void* const* d_in, const int* in_sizes, int n_in,
                              void* d_out, int out_size, void* d_ws, size_t ws_size,
                              hipStream_t stream) {
    const float* x  = (const float*)d_in[0];
    const float* xa = (const float*)d_in[1];
    const float* pw = (const float*)d_in[2];
    const int* hq   = (const int*)d_in[3];
    const int* nq   = (const int*)d_in[4];
    float* out      = (float*)d_out;

    char* ws = (char*)d_ws;
    double* dpart = (double*)(ws + OFF_DPART);
    double* ppart = (double*)(ws + OFF_PPART);
    int* cnt      = (int*)(ws + OFF_CNT);
    float* mu     = (float*)(ws + OFF_MU);
    float* sd     = (float*)(ws + OFF_SD);
    float* pd     = (float*)(ws + OFF_PD);
    float* rwn    = (float*)(ws + OFF_RWN);
    float* wn     = (float*)(ws + OFF_WN);
    float* Ctab   = (float*)(ws + OFF_CTAB);
    _Float16* G   = (_Float16*)(ws + OFF_G);

    init_hist_kernel<<<1, 256, 0, stream>>>(hq, cnt, dpart, ppart);
    normalize_kernel<<<BB, DD, 0, stream>>>(x, xa, G, ppart);
    proto_norm_kernel<<<PP, DD, 0, stream>>>(pw, wn);
    pd_kernel<<<PP, 128, 0, stream>>>(wn, pd);
    stats_kernel<<<PP, 64, 0, stream>>>(pd, cnt, rwn, mu, sd);
    ctab_kernel<<<(NN * PP + 255) / 256, 256, 0, stream>>>(hq, nq, rwn, mu, sd, Ctab);
    sim_kernel<<<dim3(NN / 128, NN / 128), 256, 0, stream>>>(G, hq, Ctab, dpart);
    finalize_kernel<<<1, 64, 0, stream>>>(dpart, ppart, out);
}

// Round 3
// 213.275 us; speedup vs baseline: 1.1780x; 1.0604x over previous
//
#include <hip/hip_runtime.h>
#include <cmath>

// Problem constants (B=4096, D=256, P=100, K=10, n=2B=8192, T=0.2)
#define BB   4096
#define DD   256
#define NN   8192
#define PP   100
#define KK   10

typedef _Float16 f16x8  __attribute__((ext_vector_type(8)));
typedef float    f32x16 __attribute__((ext_vector_type(16)));

// ---------------- workspace layout (bytes) ----------------
constexpr size_t OFF_DPART = 0;        // 64 double
constexpr size_t OFF_PPART = 512;      // 64 double
constexpr size_t OFF_CNT   = 1024;     // 100 int
constexpr size_t OFF_MU    = 1536;     // 100 f32
constexpr size_t OFF_SD    = 2048;     // 100 f32
constexpr size_t OFF_RWN   = 2560;     // 10000 f32
constexpr size_t OFF_WN    = 42560;    // 100*256 f32
constexpr size_t OFF_PI    = 144960;   // 8192 int  (perm: sorted pos -> orig)
constexpr size_t OFF_INVP  = 177728;   // 8192 int  (orig -> sorted pos)
constexpr size_t OFF_HQP   = 210496;   // 8192 int  (class at sorted pos)
constexpr size_t OFF_CTAB  = 243264;   // 8192*100 f32
constexpr size_t OFF_G     = 3520064;  // 8192*256 f16, fragment-packed (16B aligned)

// Fragment-packed G layout for mfma_f32_32x32x16_f16:
// element (row p, k) lives at ((p>>5)*16 + (k>>4))*512 + ((k>>3)&1)*256 + (p&31)*8 + (k&7)
// so lane l's A/B fragment for 32-row group g, k-chunk kc is the contiguous
// 16 B at (g*16+kc)*512 + l*8.   (A[m=l&31][k=kc*16+(l>>5)*8+e])
__device__ __forceinline__ int packed_addr(int p, int k) {
    return (((p >> 5) * 16 + (k >> 4)) << 9) + (((k >> 3) & 1) << 8) + ((p & 31) << 3) + (k & 7);
}

// ---------------- sort prep: zeros + histogram + scan + counting-sort scatter ----
__global__ void sortprep_kernel(const int* __restrict__ hq, int* __restrict__ cnt,
                                int* __restrict__ pi, int* __restrict__ invp,
                                int* __restrict__ hqp,
                                double* __restrict__ dpart, double* __restrict__ ppart) {
    __shared__ int sc[PP], so[PP];
    const int t = threadIdx.x;  // 256
    if (t < PP) sc[t] = 0;
    if (t < 64) { dpart[t] = 0.0; ppart[t] = 0.0; }
    __syncthreads();
    for (int i = t; i < NN; i += 256) atomicAdd(&sc[hq[i]], 1);
    __syncthreads();
    if (t < PP) cnt[t] = sc[t];
    if (t == 0) {
        int run = 0;
        for (int c = 0; c < PP; ++c) { so[c] = run; run += sc[c]; }
    }
    __syncthreads();
    for (int i = t; i < NN; i += 256) {
        int c = hq[i];
        int d = atomicAdd(&so[c], 1);
        pi[d] = i;
        invp[i] = d;
        hqp[d] = c;
    }
}

// ---------------- normalize x / x_aug rows -> packed f16 Gp, pos dot ----------
__global__ void normalize_kernel(const float* __restrict__ x, const float* __restrict__ xa,
                                 const int* __restrict__ invp,
                                 _Float16* __restrict__ Gp, double* __restrict__ ppart) {
    const int i = blockIdx.x;       // 0..4095 (source row)
    const int t = threadIdx.x;      // 0..255 == D
    float v1 = x[(size_t)i * DD + t];
    float v2 = xa[(size_t)i * DD + t];
    float a = v1 * v1, b = v2 * v2, c = v1 * v2;
#pragma unroll
    for (int off = 32; off > 0; off >>= 1) {
        a += __shfl_down(a, off);
        b += __shfl_down(b, off);
        c += __shfl_down(c, off);
    }
    __shared__ float sa[4], sb[4], sc[4];
    const int lane = t & 63, wv = t >> 6;
    if (lane == 0) { sa[wv] = a; sb[wv] = b; sc[wv] = c; }
    __syncthreads();
    float ta = sa[0] + sa[1] + sa[2] + sa[3];
    float tb = sb[0] + sb[1] + sb[2] + sb[3];
    float tc = sc[0] + sc[1] + sc[2] + sc[3];
    float d1 = fmaxf(sqrtf(ta), 1e-12f);
    float d2 = fmaxf(sqrtf(tb), 1e-12f);
    const int p1 = invp[i];
    const int p2 = invp[i + BB];
    Gp[packed_addr(p1, t)] = (_Float16)(v1 / d1);
    Gp[packed_addr(p2, t)] = (_Float16)(v2 / d2);
    if (t == 0) atomicAdd(&ppart[i & 63], (double)(tc / (d1 * d2)));
}

// ---------------- normalize prototype rows -> wn[100][256] f32 ----------------
__global__ void proto_norm_kernel(const float* __restrict__ pw, float* __restrict__ wn) {
    const int r = blockIdx.x;   // 0..99
    const int t = threadIdx.x;  // 0..255
    float v = pw[(size_t)r * DD + t];
    float a = v * v;
#pragma unroll
    for (int off = 32; off > 0; off >>= 1) a += __shfl_down(a, off);
    __shared__ float sa[4];
    const int lane = t & 63, wv = t >> 6;
    if (lane == 0) sa[wv] = a;
    __syncthreads();
    float ta = sa[0] + sa[1] + sa[2] + sa[3];
    float d = fmaxf(sqrtf(ta), 1e-12f);
    wn[(size_t)r * DD + t] = v / d;
}

// ---------------- fused pd row + per-class stats ----------------
// pd[a][b] = 1 - wn_a . wn_b ; then stats over row a's multiset
// { pd[a][b] x (cnt[b]-(b==a)) } U {0}: rwn row, mu[a], sd[a].
__global__ void pdstats_kernel(const float* __restrict__ wn, const int* __restrict__ cnt,
                               float* __restrict__ rwn, float* __restrict__ mu,
                               float* __restrict__ sd) {
    const int a = blockIdx.x;   // 0..99
    const int t = threadIdx.x;  // 0..127
    __shared__ float wb[DD];
    __shared__ float pdrow[PP];
    wb[t] = wn[(size_t)a * DD + t];
    wb[t + 128] = wn[(size_t)a * DD + t + 128];
    __syncthreads();
    if (t < PP) {
        const float* wc = wn + (size_t)t * DD;
        float dot = 0.f;
        for (int k = 0; k < DD; ++k) dot += wb[k] * wc[k];
        pdrow[t] = 1.0f - dot;
    }
    __syncthreads();
    if (t < 64) {
        const int lane = t;
        float vmin = 0.f, vmax = 0.f;  // eye-zero always in multiset
        for (int b = lane; b < PP; b += 64) {
            int cc = cnt[b] - (b == a ? 1 : 0);
            if (cc > 0) {
                float v = pdrow[b];
                vmin = fminf(vmin, v);
                vmax = fmaxf(vmax, v);
            }
        }
#pragma unroll
        for (int off = 32; off > 0; off >>= 1) {
            vmin = fminf(vmin, __shfl_xor(vmin, off));
            vmax = fmaxf(vmax, __shfl_xor(vmax, off));
        }
        const float den = vmax - vmin;
        const float inv = (den > 0.f) ? 1.f / den : 0.f;
        double s1 = 0.0, s2 = 0.0;
        for (int b = lane; b < PP; b += 64) {
            float v = (pdrow[b] - vmin) * inv;
            rwn[a * PP + b] = v;
            int cc = cnt[b] - (b == a ? 1 : 0);
            if (cc > 0) { double dv = v; s1 += cc * dv; s2 += cc * dv * dv; }
        }
        if (lane == 0) { double v0 = (0.0 - (double)vmin) * inv; s1 += v0; s2 += v0 * v0; }
#pragma unroll
        for (int off = 32; off > 0; off >>= 1) {
            s1 += __shfl_xor(s1, off);
            s2 += __shfl_xor(s2, off);
        }
        if (lane == 0) {
            double m = s1 / (double)NN;
            double var = (s2 - (double)NN * m * m) / (double)(NN - 1);
            mu[a] = (float)m;
            sd[a] = (float)sqrt(fmax(var, 0.0));
        }
    }
}

// ---- Ctabp[p][c] = (c in neg_q[pi[p]]) ? exp((rwn[hqp[p]][c]-mu[c])^2/(2 sd[c]^2)) : 0
__global__ void ctab_kernel(const int* __restrict__ pi, const int* __restrict__ hqp,
                            const int* __restrict__ nq, const float* __restrict__ rwn,
                            const float* __restrict__ mu, const float* __restrict__ sd,
                            float* __restrict__ Ctab) {
    int idx = blockIdx.x * 256 + threadIdx.x;  // < 819200
    if (idx >= NN * PP) return;
    int p = idx / PP;
    int c = idx - p * PP;
    const int* row = nq + (size_t)pi[p] * KK;
    bool m = false;
#pragma unroll
    for (int k = 0; k < KK; ++k) m = m || (row[k] == c);
    float v = 0.f;
    if (m) {
        float d = rwn[hqp[p] * PP + c] - mu[c];
        float s = sd[c];
        v = expf(d * d / (2.0f * s * s));
    }
    Ctab[idx] = v;
}

// ---------------- main fused GEMM: barrier-free, fragment-direct loads ----------
// denom = sum_{p!=q} exp(5*dot_pq) * Ctabp[p][hqp[q]]   (indices sorted by class)
__global__ __launch_bounds__(256) void sim_kernel(
    const _Float16* __restrict__ Gp, const int* __restrict__ hqp,
    const float* __restrict__ Ctabp, double* __restrict__ dpart) {
    const int t = threadIdx.x;
    const int lane = t & 63;
    const int wv = t >> 6;
    // 4 waves tile a 128x128 block as 2x2 of 64x64 wave-tiles
    const int i0 = blockIdx.y * 128 + (wv >> 1) * 64;
    const int j0 = blockIdx.x * 128 + (wv & 1) * 64;

    f32x16 acc[2][2] = {};

    const _Float16* pa0 = Gp + (size_t)((i0 >> 5) + 0) * 16 * 512 + lane * 8;
    const _Float16* pa1 = Gp + (size_t)((i0 >> 5) + 1) * 16 * 512 + lane * 8;
    const _Float16* pb0 = Gp + (size_t)((j0 >> 5) + 0) * 16 * 512 + lane * 8;
    const _Float16* pb1 = Gp + (size_t)((j0 >> 5) + 1) * 16 * 512 + lane * 8;

#pragma unroll
    for (int kc = 0; kc < 16; ++kc) {
        f16x8 a0 = *(const f16x8*)(pa0 + kc * 512);
        f16x8 a1 = *(const f16x8*)(pa1 + kc * 512);
        f16x8 b0 = *(const f16x8*)(pb0 + kc * 512);
        f16x8 b1 = *(const f16x8*)(pb1 + kc * 512);
        acc[0][0] = __builtin_amdgcn_mfma_f32_32x32x16_f16(a0, b0, acc[0][0], 0, 0, 0);
        acc[0][1] = __builtin_amdgcn_mfma_f32_32x32x16_f16(a0, b1, acc[0][1], 0, 0, 0);
        acc[1][0] = __builtin_amdgcn_mfma_f32_32x32x16_f16(a1, b0, acc[1][0], 0, 0, 0);
        acc[1][1] = __builtin_amdgcn_mfma_f32_32x32x16_f16(a1, b1, acc[1][1], 0, 0, 0);
    }

    // C/D layout (32x32): col = lane&31, row = (reg&3) + 8*(reg>>2) + 4*(lane>>5)
    const int cl = lane & 31, h = lane >> 5;
    const int cls0 = hqp[j0 + cl];
    const int cls1 = hqp[j0 + 32 + cl];
    float partial = 0.f;
#pragma unroll
    for (int mi = 0; mi < 2; ++mi) {
        const int rb = i0 + mi * 32 + 4 * h;
#pragma unroll
        for (int ni = 0; ni < 2; ++ni) {
            const int cls = ni ? cls1 : cls0;
            const int col = j0 + ni * 32 + cl;
#pragma unroll
            for (int r = 0; r < 16; ++r) {
                const int row = rb + (r & 3) + 8 * (r >> 2);
                const float coef = Ctabp[(size_t)row * PP + cls];  // sorted -> ~2-4 lines
                const float e = __expf(acc[mi][ni][r] * 5.0f);
                partial += (row != col) ? e * coef : 0.f;
            }
        }
    }
#pragma unroll
    for (int off = 32; off > 0; off >>= 1) partial += __shfl_down(partial, off);
    __shared__ float wsum[4];
    if (lane == 0) wsum[wv] = partial;
    __syncthreads();
    if (t == 0)
        atomicAdd(&dpart[(blockIdx.y * 64 + blockIdx.x) & 63],
                  (double)(wsum[0] + wsum[1] + wsum[2] + wsum[3]));
}

// ---------------- finalize ----------------
__global__ void finalize_kernel(const double* __restrict__ dpart,
                                const double* __restrict__ ppart, float* __restrict__ out) {
    const int lane = threadIdx.x;  // 64
    double d = dpart[lane], p = ppart[lane];
#pragma unroll
    for (int off = 32; off > 0; off >>= 1) {
        d += __shfl_down(d, off);
        p += __shfl_down(p, off);
    }
    if (lane == 0) out[0] = (float)(log(d) - p * (5.0 / 4096.0));
}

extern "C" void kernel_launch(void* const* d_in, const int* in_sizes, int n_in,
                              void* d_out, int out_size, void* d_ws, size_t ws_size,
                              hipStream_t stream) {
    const float* x  = (const float*)d_in[0];
    const float* xa = (const float*)d_in[1];
    const float* pw = (const float*)d_in[2];
    const int* hq   = (const int*)d_in[3];
    const int* nq   = (const int*)d_in[4];
    float* out      = (float*)d_out;

    char* ws = (char*)d_ws;
    double* dpart = (double*)(ws + OFF_DPART);
    double* ppart = (double*)(ws + OFF_PPART);
    int* cnt      = (int*)(ws + OFF_CNT);
    float* mu     = (float*)(ws + OFF_MU);
    float* sd     = (float*)(ws + OFF_SD);
    float* rwn    = (float*)(ws + OFF_RWN);
    float* wn     = (float*)(ws + OFF_WN);
    int* pi       = (int*)(ws + OFF_PI);
    int* invp     = (int*)(ws + OFF_INVP);
    int* hqp      = (int*)(ws + OFF_HQP);
    float* Ctabp  = (float*)(ws + OFF_CTAB);
    _Float16* Gp  = (_Float16*)(ws + OFF_G);

    sortprep_kernel<<<1, 256, 0, stream>>>(hq, cnt, pi, invp, hqp, dpart, ppart);
    normalize_kernel<<<BB, DD, 0, stream>>>(x, xa, invp, Gp, ppart);
    proto_norm_kernel<<<PP, DD, 0, stream>>>(pw, wn);
    pdstats_kernel<<<PP, 128, 0, stream>>>(wn, cnt, rwn, mu, sd);
    ctab_kernel<<<(NN * PP + 255) / 256, 256, 0, stream>>>(pi, hqp, nq, rwn, mu, sd, Ctabp);
    sim_kernel<<<dim3(NN / 128, NN / 128), 256, 0, stream>>>(Gp, hqp, Ctabp, dpart);
    finalize_kernel<<<1, 64, 0, stream>>>(dpart, ppart, out);
}